// Round 1
// baseline (112.629 us; speedup 1.0000x reference)
//
#include <hip/hip_runtime.h>

// Problem constants: B=1024, F=33, D=128, A=128, P=F*(F-1)/2=528
#define FN 33
#define DN 128
#define AN 128
#define PN 528
#define XS 136     // fp16 row stride for xh in LDS (272 B, 16B-aligned, non-pow2)
#define TS 36      // float row stride for attn2d (144 B)

typedef __attribute__((ext_vector_type(8))) _Float16 half8;
typedef __attribute__((ext_vector_type(4))) float f32x4;
typedef __attribute__((ext_vector_type(4))) unsigned int u32x4;

__device__ __forceinline__ unsigned int pkrtz(float a, float b) {
  return __builtin_bit_cast(unsigned int, __builtin_amdgcn_cvt_pkrtz(a, b));
}

// sum over the 16-lane DPP row via row_ror rotations (VALU pipe, no LDS)
__device__ __forceinline__ float row_sum16(float v) {
  v += __builtin_bit_cast(float, __builtin_amdgcn_update_dpp(0, __builtin_bit_cast(int, v), 0x128, 0xF, 0xF, false));
  v += __builtin_bit_cast(float, __builtin_amdgcn_update_dpp(0, __builtin_bit_cast(int, v), 0x124, 0xF, 0xF, false));
  v += __builtin_bit_cast(float, __builtin_amdgcn_update_dpp(0, __builtin_bit_cast(int, v), 0x122, 0xF, 0xF, false));
  v += __builtin_bit_cast(float, __builtin_amdgcn_update_dpp(0, __builtin_bit_cast(int, v), 0x121, 0xF, 0xF, false));
  return v;
}

// 2-D wave split: wave = mh*2 + nh. Each wave computes m-tiles of its half
// against 64 output columns (4 n-blocks). Bf = 64 VGPRs/wave (was 128),
// no W LDS staging (was 32 KB) -> 4 waves/SIMD, 4 blocks/CU, single round.
__global__ __launch_bounds__(256, 4)
void afm_kernel(const float* __restrict__ gnn, const float* __restrict__ xg,
                const float* __restrict__ Wg,  const float* __restrict__ bg,
                float* __restrict__ out)
{
  __shared__ __align__(16) _Float16 xh[FN * XS];        // 8976 B, x[b] as fp16
  __shared__ __align__(16) float attn2d[FN * TS];       // 4752 B, unnormalized exp
  __shared__ __align__(16) float sp[2][PN];             // 4224 B, per-nh score partials
  __shared__ __align__(16) float part[256];             // epilogue partials
  __shared__ unsigned short rowcol[PN];                 // i | (j<<8)
  __shared__ float red[8];

  const int tid  = threadIdx.x;
  const int b    = blockIdx.x;
  const int wave = tid >> 6;
  const int lane = tid & 63;
  const int q    = lane >> 4;   // quad 0..3
  const int u    = lane & 15;
  const int nh   = wave & 1;    // n-half: columns [nh*64, nh*64+64)
  const int mh   = wave >> 1;   // m-half: tiles [0,17) or [17,33)

  // ---------------- W quadrant: global -> registers (fp16), issued early ----
  // Bf[nn][kk]: lane holds W[a = (nh*4+nn)*16+u][k = kk*32 + q*8 .. +8]
  half8 Bf[4][4];
  float garr[4], barr[4];
  #pragma unroll
  for (int nn = 0; nn < 4; nn++) {
    const int a = (nh * 4 + nn) * 16 + u;
    const float* src = Wg + (size_t)a * DN + q * 8;
    #pragma unroll
    for (int kk = 0; kk < 4; kk++) {
      f32x4 w0 = *(const f32x4*)(src + kk * 32);
      f32x4 w1 = *(const f32x4*)(src + kk * 32 + 4);
      u32x4 pk;
      pk.x = pkrtz(w0.x, w0.y);
      pk.y = pkrtz(w0.z, w0.w);
      pk.z = pkrtz(w1.x, w1.y);
      pk.w = pkrtz(w1.z, w1.w);
      Bf[nn][kk] = __builtin_bit_cast(half8, pk);
      asm volatile("" : "+v"(Bf[nn][kk]));   // pin: forbid remat/sinking
    }
    garr[nn] = gnn[(size_t)b * AN + a];
    barr[nn] = bg[a];
    asm volatile("" : "+v"(garr[nn]), "+v"(barr[nn]));
  }

  // ---------------- staging (x -> fp16 LDS, pair table, attn2d zero) --------
  for (int idx = tid; idx < FN * TS; idx += 256) attn2d[idx] = 0.0f;

  const f32x4* xg4 = (const f32x4*)(xg + (size_t)b * FN * DN);
  for (int idx = tid; idx < (FN * DN) / 4; idx += 256) {   // 1056 float4
    f32x4 v = xg4[idx];
    int i  = idx >> 5;           // field row
    int d0 = (idx & 31) << 2;
    *(uint2*)&xh[i * XS + d0] = make_uint2(pkrtz(v.x, v.y), pkrtz(v.z, v.w));
  }
  for (int p = tid; p < PN; p += 256) {
    int i = 0, rem = p;
    while (rem >= FN - 1 - i) { rem -= FN - 1 - i; i++; }
    rowcol[p] = (unsigned short)(i | ((i + 1 + rem) << 8));
  }
  __syncthreads();

  // ---------------- fm matmul + score partials (fp16 MFMA) ------------------
  const int mt_beg = mh ? 17 : 0;
  const int mt_end = mh ? 33 : 17;
  unsigned int rc_next = rowcol[mt_beg * 16 + u];
  for (int mt = mt_beg; mt < mt_end; ++mt) {
    const unsigned int rc = rc_next;
    if (mt + 1 < mt_end) rc_next = rowcol[(mt + 1) * 16 + u];
    const int r = rc & 255, c = rc >> 8;
    const _Float16* xr_base = &xh[r * XS + q * 8];
    const _Float16* xc_base = &xh[c * XS + q * 8];

    f32x4 acc[4];
    #pragma unroll
    for (int nn = 0; nn < 4; nn++) acc[nn] = (f32x4){0.f, 0.f, 0.f, 0.f};

    #pragma unroll
    for (int kk = 0; kk < 4; kk++) {
      half8 xr = *(const half8*)(xr_base + kk * 32);
      half8 xc = *(const half8*)(xc_base + kk * 32);
      half8 af = xr * xc;                        // v_pk_mul_f16
      #pragma unroll
      for (int nn = 0; nn < 4; nn++)
        acc[nn] = __builtin_amdgcn_mfma_f32_16x16x32_f16(af, Bf[nn][kk], acc[nn], 0, 0, 0);
    }

    // fused bias + relu + gnn dot: D[row=q*4+rr][col=u], a = (nh*4+nn)*16+u
    float sc[4] = {0.f, 0.f, 0.f, 0.f};
    #pragma unroll
    for (int nn = 0; nn < 4; nn++)
      #pragma unroll
      for (int rr = 0; rr < 4; rr++) {
        float fmv = fmaxf(acc[nn][rr] + barr[nn], 0.f);
        sc[rr] = fmaf(fmv, garr[nn], sc[rr]);
      }
    #pragma unroll
    for (int rr = 0; rr < 4; rr++) sc[rr] = row_sum16(sc[rr]);
    if (u == 0)
      *(f32x4*)&sp[nh][mt * 16 + q * 4] = (f32x4){sc[0], sc[1], sc[2], sc[3]};
  }
  __syncthreads();

  // ---------------- softmax over 528 scores (sum the two nh partials) -------
  float s0 = sp[0][tid] + sp[1][tid];
  float s1 = sp[0][tid + 256] + sp[1][tid + 256];
  float s2 = (tid < 16) ? (sp[0][tid + 512] + sp[1][tid + 512]) : -3.4e38f;
  float m = fmaxf(fmaxf(s0, s1), s2);
  #pragma unroll
  for (int off = 32; off >= 1; off >>= 1) m = fmaxf(m, __shfl_xor(m, off, 64));
  if (lane == 0) red[wave] = m;
  __syncthreads();
  const float smax = fmaxf(fmaxf(red[0], red[1]), fmaxf(red[2], red[3]));

  float e0 = __expf(s0 - smax);
  float e1 = __expf(s1 - smax);
  float e2 = (tid < 16) ? __expf(s2 - smax) : 0.f;
  {
    unsigned int rc = rowcol[tid];
    attn2d[(rc & 255) * TS + ((rc >> 8) - (rc & 255) - 1)] = e0;
    rc = rowcol[tid + 256];
    attn2d[(rc & 255) * TS + ((rc >> 8) - (rc & 255) - 1)] = e1;
    if (tid < 16) {
      rc = rowcol[tid + 512];
      attn2d[(rc & 255) * TS + ((rc >> 8) - (rc & 255) - 1)] = e2;
    }
  }
  float lsum = e0 + e1 + e2;
  #pragma unroll
  for (int off = 32; off >= 1; off >>= 1) lsum += __shfl_xor(lsum, off, 64);
  if (lane == 0) red[4 + wave] = lsum;
  __syncthreads();
  const float Z = red[4] + red[5] + red[6] + red[7];

  // ---------------- epilogue: out = [gnn, 100 * attn @ inner] ---------------
  // parity-interleaved i-split (even i -> half 0, odd i -> half 1): balanced
  // 272/256 pair-FMAs per half (was 392/136). i stays compile-time so xcol[]
  // is statically indexed (no scratch).
  {
    const int d = tid & 127;
    const int h = tid >> 7;          // parity half (wave-uniform)
    float xcol[36];
    #pragma unroll
    for (int i = 0; i < FN; i++) xcol[i] = (float)xh[i * XS + d];
    xcol[33] = 0.f; xcol[34] = 0.f; xcol[35] = 0.f;

    float acc = 0.f;
    #pragma unroll
    for (int i = 0; i < 32; i++) {
      if ((i & 1) != h) continue;
      const int L = FN - 1 - i;                  // pairs (i, i+1+jj), jj < L
      const int nf4 = (L + 3) >> 2;
      float ti = 0.f;
      #pragma unroll
      for (int t = 0; t < nf4; t++) {
        f32x4 a4 = *(const f32x4*)&attn2d[i * TS + t * 4];  // pad entries are 0
        ti = fmaf(a4.x, xcol[i + 1 + t * 4 + 0], ti);
        ti = fmaf(a4.y, xcol[i + 1 + t * 4 + 1], ti);
        ti = fmaf(a4.z, xcol[i + 1 + t * 4 + 2], ti);
        ti = fmaf(a4.w, xcol[i + 1 + t * 4 + 3], ti);
      }
      acc = fmaf(xcol[i], ti, acc);
    }
    part[tid] = acc;
  }
  __syncthreads();
  if (tid < DN) {
    float tot = part[tid] + part[tid + 128];
    out[(size_t)b * (AN + DN) + AN + tid] = tot * (100.0f / Z);
  } else {
    const int a = tid - 128;
    out[(size_t)b * (AN + DN) + a] = gnn[(size_t)b * AN + a];
  }
}

extern "C" void kernel_launch(void* const* d_in, const int* in_sizes, int n_in,
                              void* d_out, int out_size, void* d_ws, size_t ws_size,
                              hipStream_t stream) {
  (void)n_in; (void)out_size; (void)d_ws; (void)ws_size;
  const float* gnn  = (const float*)d_in[0];
  const float* x    = (const float*)d_in[1];
  const float* W    = (const float*)d_in[2];
  const float* bias = (const float*)d_in[3];
  float* out = (float*)d_out;
  const int Bn = in_sizes[0] / AN;   // 1024
  afm_kernel<<<dim3(Bn), dim3(256), 0, stream>>>(gnn, x, W, bias, out);
}

// Round 2
// 110.895 us; speedup vs baseline: 1.0156x; 1.0156x over previous
//
#include <hip/hip_runtime.h>

// Problem constants: B=1024, F=33, D=128, A=128, P=F*(F-1)/2=528
#define FN 33
#define DN 128
#define AN 128
#define PN 528
#define XS 136     // fp16 row stride for xh in LDS (272 B, 16B-aligned, non-pow2)
#define TS 36      // float row stride for attn2d (144 B)

typedef __attribute__((ext_vector_type(8))) _Float16 half8;
typedef __attribute__((ext_vector_type(4))) float f32x4;
typedef __attribute__((ext_vector_type(4))) unsigned int u32x4;

__device__ __forceinline__ unsigned int pkrtz(float a, float b) {
  return __builtin_bit_cast(unsigned int, __builtin_amdgcn_cvt_pkrtz(a, b));
}

// sum over the 16-lane DPP row via row_ror rotations (VALU pipe, no LDS)
__device__ __forceinline__ float row_sum16(float v) {
  v += __builtin_bit_cast(float, __builtin_amdgcn_update_dpp(0, __builtin_bit_cast(int, v), 0x128, 0xF, 0xF, false));
  v += __builtin_bit_cast(float, __builtin_amdgcn_update_dpp(0, __builtin_bit_cast(int, v), 0x124, 0xF, 0xF, false));
  v += __builtin_bit_cast(float, __builtin_amdgcn_update_dpp(0, __builtin_bit_cast(int, v), 0x122, 0xF, 0xF, false));
  v += __builtin_bit_cast(float, __builtin_amdgcn_update_dpp(0, __builtin_bit_cast(int, v), 0x121, 0xF, 0xF, false));
  return v;
}

// R2: latency-stall attack. Waves = 4 n-quarters (Bf[2][4] = 32 VGPR); each
// wave walks ALL 33 m-tiles as independent PAIRS -> 2x independent dep-chains
// (loads, MFMA chains, DPP trees) at every point, filling the stalls that
// R0/R1 (both ~50 us, all pipes <35%) could not.
__global__ __launch_bounds__(256, 4)
void afm_kernel(const float* __restrict__ gnn, const float* __restrict__ xg,
                const float* __restrict__ Wg,  const float* __restrict__ bg,
                float* __restrict__ out)
{
  __shared__ __align__(16) _Float16 xh[FN * XS];        // 8976 B, x[b] as fp16
  __shared__ __align__(16) float attn2d[FN * TS];       // 4752 B, unnormalized exp
  __shared__ __align__(16) float sp[4][PN];             // 8448 B, per-quarter score partials
  __shared__ __align__(16) float part[256];             // epilogue partials
  __shared__ unsigned short rowcol[PN];                 // i | (j<<8)
  __shared__ float red[8];

  const int tid  = threadIdx.x;
  const int b    = blockIdx.x;
  const int wave = tid >> 6;
  const int lane = tid & 63;
  const int q    = lane >> 4;   // quad 0..3
  const int u    = lane & 15;
  const int nq   = wave;        // n-quarter: columns [nq*32, nq*32+32)

  // ---------------- W quarter: global -> registers (fp16), issued early -----
  // Bf[nn][kk]: lane holds W[a = nq*32 + nn*16 + u][k = kk*32 + q*8 .. +8]
  half8 Bf[2][4];
  float garr[2], barr[2];
  #pragma unroll
  for (int nn = 0; nn < 2; nn++) {
    const int a = nq * 32 + nn * 16 + u;
    const float* src = Wg + (size_t)a * DN + q * 8;
    #pragma unroll
    for (int kk = 0; kk < 4; kk++) {
      f32x4 w0 = *(const f32x4*)(src + kk * 32);
      f32x4 w1 = *(const f32x4*)(src + kk * 32 + 4);
      u32x4 pk;
      pk.x = pkrtz(w0.x, w0.y);
      pk.y = pkrtz(w0.z, w0.w);
      pk.z = pkrtz(w1.x, w1.y);
      pk.w = pkrtz(w1.z, w1.w);
      Bf[nn][kk] = __builtin_bit_cast(half8, pk);
      asm volatile("" : "+v"(Bf[nn][kk]));   // pin: forbid remat/sinking
    }
    garr[nn] = gnn[(size_t)b * AN + a];
    barr[nn] = bg[a];
    asm volatile("" : "+v"(garr[nn]), "+v"(barr[nn]));
  }

  // ---------------- staging (x -> fp16 LDS, pair table, attn2d zero) --------
  for (int idx = tid; idx < FN * TS; idx += 256) attn2d[idx] = 0.0f;

  const f32x4* xg4 = (const f32x4*)(xg + (size_t)b * FN * DN);
  for (int idx = tid; idx < (FN * DN) / 4; idx += 256) {   // 1056 float4
    f32x4 v = xg4[idx];
    int i  = idx >> 5;           // field row
    int d0 = (idx & 31) << 2;
    *(uint2*)&xh[i * XS + d0] = make_uint2(pkrtz(v.x, v.y), pkrtz(v.z, v.w));
  }
  for (int p = tid; p < PN; p += 256) {
    int i = 0, rem = p;
    while (rem >= FN - 1 - i) { rem -= FN - 1 - i; i++; }
    rowcol[p] = (unsigned short)(i | ((i + 1 + rem) << 8));
  }
  __syncthreads();

  // ---------------- fm matmul + score partials: 16 tile-PAIRS + 1 tail ------
  unsigned int rc0 = rowcol[u];         // tile 2t   (t=0)
  unsigned int rc1 = rowcol[16 + u];    // tile 2t+1 (t=0)
  for (int t = 0; t < 16; ++t) {
    const int r0 = rc0 & 255, c0 = rc0 >> 8;
    const int r1 = rc1 & 255, c1 = rc1 >> 8;
    const _Float16* xr0 = &xh[r0 * XS + q * 8];
    const _Float16* xc0 = &xh[c0 * XS + q * 8];
    const _Float16* xr1 = &xh[r1 * XS + q * 8];
    const _Float16* xc1 = &xh[c1 * XS + q * 8];
    // prefetch next pair's rowcol (hide LDS latency behind this pair's work)
    if (t < 15) {
      rc0 = rowcol[(t + 1) * 32 + u];
      rc1 = rowcol[(t + 1) * 32 + 16 + u];
    } else {
      rc0 = rowcol[512 + u];            // tail tile 32
    }

    f32x4 acc0[2], acc1[2];
    #pragma unroll
    for (int nn = 0; nn < 2; nn++) {
      acc0[nn] = (f32x4){0.f, 0.f, 0.f, 0.f};
      acc1[nn] = (f32x4){0.f, 0.f, 0.f, 0.f};
    }

    __builtin_amdgcn_s_setprio(1);
    #pragma unroll
    for (int kk = 0; kk < 4; kk++) {
      half8 a0 = *(const half8*)(xr0 + kk * 32) * *(const half8*)(xc0 + kk * 32);
      half8 a1 = *(const half8*)(xr1 + kk * 32) * *(const half8*)(xc1 + kk * 32);
      acc0[0] = __builtin_amdgcn_mfma_f32_16x16x32_f16(a0, Bf[0][kk], acc0[0], 0, 0, 0);
      acc1[0] = __builtin_amdgcn_mfma_f32_16x16x32_f16(a1, Bf[0][kk], acc1[0], 0, 0, 0);
      acc0[1] = __builtin_amdgcn_mfma_f32_16x16x32_f16(a0, Bf[1][kk], acc0[1], 0, 0, 0);
      acc1[1] = __builtin_amdgcn_mfma_f32_16x16x32_f16(a1, Bf[1][kk], acc1[1], 0, 0, 0);
    }
    __builtin_amdgcn_s_setprio(0);

    // fused bias + relu + gnn dot, both tiles interleaved (8 independent trees)
    float sc0[4] = {0.f, 0.f, 0.f, 0.f};
    float sc1[4] = {0.f, 0.f, 0.f, 0.f};
    #pragma unroll
    for (int nn = 0; nn < 2; nn++)
      #pragma unroll
      for (int rr = 0; rr < 4; rr++) {
        sc0[rr] = fmaf(fmaxf(acc0[nn][rr] + barr[nn], 0.f), garr[nn], sc0[rr]);
        sc1[rr] = fmaf(fmaxf(acc1[nn][rr] + barr[nn], 0.f), garr[nn], sc1[rr]);
      }
    #pragma unroll
    for (int rr = 0; rr < 4; rr++) {
      sc0[rr] = row_sum16(sc0[rr]);
      sc1[rr] = row_sum16(sc1[rr]);
    }
    if (u == 0) {
      *(f32x4*)&sp[nq][t * 32 + q * 4]      = (f32x4){sc0[0], sc0[1], sc0[2], sc0[3]};
      *(f32x4*)&sp[nq][t * 32 + 16 + q * 4] = (f32x4){sc1[0], sc1[1], sc1[2], sc1[3]};
    }
  }
  // ---- tail tile 32 (rows 512..527) ----
  {
    const int r0 = rc0 & 255, c0 = rc0 >> 8;
    const _Float16* xr0 = &xh[r0 * XS + q * 8];
    const _Float16* xc0 = &xh[c0 * XS + q * 8];
    f32x4 acc0[2];
    acc0[0] = (f32x4){0.f, 0.f, 0.f, 0.f};
    acc0[1] = (f32x4){0.f, 0.f, 0.f, 0.f};
    __builtin_amdgcn_s_setprio(1);
    #pragma unroll
    for (int kk = 0; kk < 4; kk++) {
      half8 a0 = *(const half8*)(xr0 + kk * 32) * *(const half8*)(xc0 + kk * 32);
      acc0[0] = __builtin_amdgcn_mfma_f32_16x16x32_f16(a0, Bf[0][kk], acc0[0], 0, 0, 0);
      acc0[1] = __builtin_amdgcn_mfma_f32_16x16x32_f16(a0, Bf[1][kk], acc0[1], 0, 0, 0);
    }
    __builtin_amdgcn_s_setprio(0);
    float sc0[4] = {0.f, 0.f, 0.f, 0.f};
    #pragma unroll
    for (int nn = 0; nn < 2; nn++)
      #pragma unroll
      for (int rr = 0; rr < 4; rr++)
        sc0[rr] = fmaf(fmaxf(acc0[nn][rr] + barr[nn], 0.f), garr[nn], sc0[rr]);
    #pragma unroll
    for (int rr = 0; rr < 4; rr++) sc0[rr] = row_sum16(sc0[rr]);
    if (u == 0)
      *(f32x4*)&sp[nq][512 + q * 4] = (f32x4){sc0[0], sc0[1], sc0[2], sc0[3]};
  }
  __syncthreads();

  // ---------------- softmax over 528 scores (sum the 4 quarter partials) ----
  float s0 = (sp[0][tid] + sp[1][tid]) + (sp[2][tid] + sp[3][tid]);
  float s1 = (sp[0][tid + 256] + sp[1][tid + 256]) + (sp[2][tid + 256] + sp[3][tid + 256]);
  float s2 = (tid < 16)
           ? ((sp[0][tid + 512] + sp[1][tid + 512]) + (sp[2][tid + 512] + sp[3][tid + 512]))
           : -3.4e38f;
  float m = fmaxf(fmaxf(s0, s1), s2);
  #pragma unroll
  for (int off = 32; off >= 1; off >>= 1) m = fmaxf(m, __shfl_xor(m, off, 64));
  if (lane == 0) red[wave] = m;
  __syncthreads();
  const float smax = fmaxf(fmaxf(red[0], red[1]), fmaxf(red[2], red[3]));

  float e0 = __expf(s0 - smax);
  float e1 = __expf(s1 - smax);
  float e2 = (tid < 16) ? __expf(s2 - smax) : 0.f;
  {
    unsigned int rc = rowcol[tid];
    attn2d[(rc & 255) * TS + ((rc >> 8) - (rc & 255) - 1)] = e0;
    rc = rowcol[tid + 256];
    attn2d[(rc & 255) * TS + ((rc >> 8) - (rc & 255) - 1)] = e1;
    if (tid < 16) {
      rc = rowcol[tid + 512];
      attn2d[(rc & 255) * TS + ((rc >> 8) - (rc & 255) - 1)] = e2;
    }
  }
  float lsum = e0 + e1 + e2;
  #pragma unroll
  for (int off = 32; off >= 1; off >>= 1) lsum += __shfl_xor(lsum, off, 64);
  if (lane == 0) red[4 + wave] = lsum;
  __syncthreads();
  const float Z = red[4] + red[5] + red[6] + red[7];

  // ---------------- epilogue: out = [gnn, 100 * attn @ inner] ---------------
  // parity-interleaved i-split (even i -> half 0, odd i -> half 1): balanced
  // 272/256 pair-FMAs per half. i stays compile-time so xcol[] is statically
  // indexed (no scratch).
  {
    const int d = tid & 127;
    const int h = tid >> 7;          // parity half (wave-uniform)
    float xcol[36];
    #pragma unroll
    for (int i = 0; i < FN; i++) xcol[i] = (float)xh[i * XS + d];
    xcol[33] = 0.f; xcol[34] = 0.f; xcol[35] = 0.f;

    float acc = 0.f;
    #pragma unroll
    for (int i = 0; i < 32; i++) {
      if ((i & 1) != h) continue;
      const int L = FN - 1 - i;                  // pairs (i, i+1+jj), jj < L
      const int nf4 = (L + 3) >> 2;
      float ti = 0.f;
      #pragma unroll
      for (int t = 0; t < nf4; t++) {
        f32x4 a4 = *(const f32x4*)&attn2d[i * TS + t * 4];  // pad entries are 0
        ti = fmaf(a4.x, xcol[i + 1 + t * 4 + 0], ti);
        ti = fmaf(a4.y, xcol[i + 1 + t * 4 + 1], ti);
        ti = fmaf(a4.z, xcol[i + 1 + t * 4 + 2], ti);
        ti = fmaf(a4.w, xcol[i + 1 + t * 4 + 3], ti);
      }
      acc = fmaf(xcol[i], ti, acc);
    }
    part[tid] = acc;
  }
  __syncthreads();
  if (tid < DN) {
    float tot = part[tid] + part[tid + 128];
    out[(size_t)b * (AN + DN) + AN + tid] = tot * (100.0f / Z);
  } else {
    const int a = tid - 128;
    out[(size_t)b * (AN + DN) + a] = gnn[(size_t)b * AN + a];
  }
}

extern "C" void kernel_launch(void* const* d_in, const int* in_sizes, int n_in,
                              void* d_out, int out_size, void* d_ws, size_t ws_size,
                              hipStream_t stream) {
  (void)n_in; (void)out_size; (void)d_ws; (void)ws_size;
  const float* gnn  = (const float*)d_in[0];
  const float* x    = (const float*)d_in[1];
  const float* W    = (const float*)d_in[2];
  const float* bias = (const float*)d_in[3];
  float* out = (float*)d_out;
  const int Bn = in_sizes[0] / AN;   // 1024
  afm_kernel<<<dim3(Bn), dim3(256), 0, stream>>>(gnn, x, W, bias, out);
}